// Round 20
// baseline (151.497 us; speedup 1.0000x reference)
//
#include <hip/hip_runtime.h>
#include <hip/hip_bf16.h>
#include <math.h>

#define NTOK   16384
#define NEXP   64
#define HID    4096
#define KSEL   8
#define EPS    7.5e-5f
#define NSPLIT 4
#define KSZ    (HID / NSPLIT)
#define RB     512            // rowwise blocks (32 rows each)

typedef __attribute__((ext_vector_type(8))) short short8;
typedef __attribute__((ext_vector_type(4))) float f32x4;

// d_out element offsets (f32 elements; int outputs stored as float values)
#define O_LOGITS 0u
#define O_PROBS  1048576u
#define O_TIDX   1179648u
#define O_GROUP  1310720u
#define O_IDX    1310784u
#define O_TPE    1441856u
#define O_LB     1441920u
#define O_ZL     1441921u

// ws byte offsets
#define W_LSQP    4096u       // 512 f32 per-block z-loss partials
#define W_TPE     8192u       // 64 int
#define W_PST     12288u      // 64 f32
#define W_EBASE   16384u      // 64 int
#define W_CBE     131072u     // 512*64 int per-block expert counts
#define W_PREF    393216u     // 512*64 int within-expert block prefixes
#define W_PSUM    655360u     // 512*128 f32 per-block half probsum partials
#define W_FLAT    1048576u    // 131072 int final expert ids
#define W_RNK     1572864u    // 131072 int within-block stable ranks
#define W_WF      2097152u    // 1 MB: W packed as MFMA B-frags bf16 hi/lo
#define W_PART    4194304u    // NSPLIT x 4 MB f32 partials
#define PART_STRIDE 1048576ull

// round-to-nearest-even f32 -> bf16 bits
__device__ __forceinline__ unsigned short f2bf(float f) {
  unsigned u = __float_as_uint(f);
  return (unsigned short)((u + 0x7fffu + ((u >> 16) & 1u)) >> 16);
}

__device__ __forceinline__ void gload16(const void* g, void* l) {
  __builtin_amdgcn_global_load_lds((const __attribute__((address_space(1))) unsigned int*)g,
                                   (__attribute__((address_space(3))) unsigned int*)l, 16, 0, 0);
}

// ---------------------------------------------------------------------------
// prep: pack W into MFMA B-frags (bf16 hi/lo).
__global__ __launch_bounds__(256) void k_prep(const float* __restrict__ w,
                                              short8* __restrict__ wf) {
  const int kk   = blockIdx.x;
  const int nb   = threadIdx.x >> 6;
  const int lane = threadIdx.x & 63;
  const int n    = nb * 16 + (lane & 15);
  const int kb   = kk * 32 + (lane >> 4) * 8;
  const float4* wp = (const float4*)(w + (size_t)n * HID + kb);
  float4 f0 = wp[0], f1 = wp[1];
  float fv[8] = {f0.x, f0.y, f0.z, f0.w, f1.x, f1.y, f1.z, f1.w};
  short8 hi, lo;
#pragma unroll
  for (int j = 0; j < 8; ++j) {
    unsigned short h = f2bf(fv[j]);
    hi[j] = (short)h;
    float r = fv[j] - __uint_as_float((unsigned)h << 16);
    lo[j] = (short)f2bf(r);
  }
  size_t base = ((size_t)(kk * 4 + nb) * 2) * 64 + lane;
  wf[base] = hi;
  wf[base + 64] = lo;
}

// ---------------------------------------------------------------------------
// MFMA router GEMM (R8-exact, measured ~56us).
__global__ __launch_bounds__(256, 4) void k_gemm(const float* __restrict__ x,
                                                 const short8* __restrict__ wf,
                                                 float* __restrict__ part) {
  __shared__ short8 wl[2][512];   // 2 x 8 KB
  const int tid  = threadIdx.x;
  const int wv   = tid >> 6;
  const int lane = tid & 63;
  const int t0   = blockIdx.x * 64;
  const int k0   = blockIdx.y * KSZ;
  const int row  = t0 + wv * 16 + (lane & 15);

  const float* xp = x + (size_t)row * HID + k0 + (lane >> 4) * 8;
  const short8* wbase = wf + (size_t)(k0 >> 5) * 512;

  auto stage = [&](int c, int b) {
    const short8* src = wbase + (size_t)c * 512;
#pragma unroll
    for (int r = 0; r < 2; ++r) {
      const int o = r * 256 + wv * 64;       // wave-uniform LDS base
      gload16(src + o + lane, &wl[b][o]);    // lane*16B added by HW
    }
  };

  f32x4 acc[4] = {{0,0,0,0},{0,0,0,0},{0,0,0,0},{0,0,0,0}};

  stage(0, 0);
  __syncthreads();
  const int nch = KSZ >> 5;   // 32
  for (int c = 0; c < nch; ++c) {
    const int b = c & 1;
    if (c + 1 < nch) stage(c + 1, b ^ 1);

    const float4* xq = (const float4*)(xp + c * 32);
    float4 f0 = xq[0], f1 = xq[1];
    unsigned xb[8] = {__float_as_uint(f0.x), __float_as_uint(f0.y),
                      __float_as_uint(f0.z), __float_as_uint(f0.w),
                      __float_as_uint(f1.x), __float_as_uint(f1.y),
                      __float_as_uint(f1.z), __float_as_uint(f1.w)};
    union { unsigned u[4]; short8 s; } ua, ul;
#pragma unroll
    for (int p = 0; p < 4; ++p) {
      unsigned b0 = xb[2 * p], b1 = xb[2 * p + 1];
      ua.u[p] = __builtin_amdgcn_perm(b1, b0, 0x07060302u);
      float r0 = __uint_as_float(b0) - __uint_as_float(b0 & 0xffff0000u);
      float r1 = __uint_as_float(b1) - __uint_as_float(b1 & 0xffff0000u);
      unsigned t0b = __float_as_uint(r0), t1b = __float_as_uint(r1);
      t0b += 0x7fffu + ((t0b >> 16) & 1u);
      t1b += 0x7fffu + ((t1b >> 16) & 1u);
      ul.u[p] = __builtin_amdgcn_perm(t1b, t0b, 0x07060302u);
    }
    short8 ah = ua.s, al = ul.s;

#pragma unroll
    for (int nb = 0; nb < 4; ++nb) {
      short8 bh = wl[b][nb * 128 + lane];
      short8 bl = wl[b][nb * 128 + 64 + lane];
      acc[nb] = __builtin_amdgcn_mfma_f32_16x16x32_bf16(ah, bh, acc[nb], 0, 0, 0);
      acc[nb] = __builtin_amdgcn_mfma_f32_16x16x32_bf16(al, bh, acc[nb], 0, 0, 0);
      acc[nb] = __builtin_amdgcn_mfma_f32_16x16x32_bf16(ah, bl, acc[nb], 0, 0, 0);
    }
    __syncthreads();
  }

  float* p = part + (size_t)blockIdx.y * PART_STRIDE;
  const int mrow = t0 + wv * 16 + (lane >> 4) * 4;
  const int col  = lane & 15;
#pragma unroll
  for (int nb = 0; nb < 4; ++nb)
#pragma unroll
    for (int r = 0; r < 4; ++r)
      p[(size_t)(mrow + r) * 64 + nb * 16 + col] = acc[nb][r];
}

// ---------------------------------------------------------------------------
// Split-K reduce, 1024 blocks (R3-proven).
__global__ __launch_bounds__(256) void k_reduce(const float* __restrict__ part,
                                                float* __restrict__ out_logits) {
  unsigned i4 = blockIdx.x * 256u + threadIdx.x;
  const float4* p4 = (const float4*)part;
  float4 v = p4[i4];
#pragma unroll
  for (int s = 1; s < NSPLIT; ++s) {
    float4 a = p4[(size_t)s * (PART_STRIDE / 4) + i4];
    v.x += a.x; v.y += a.y; v.z += a.z; v.w += a.w;
  }
  ((float4*)out_logits)[i4] = v;
}

// ---------------------------------------------------------------------------
// Rowwise, 512 blocks x 32 rows (2 blocks/CU = 8 waves/CU): per-row math
// identical to R19 (bit-identical discrete outputs), ballot ranks with rows
// in lanes 0..31.
__global__ __launch_bounds__(256) void k_rowwise(const float* __restrict__ lg,
                                                 const float* __restrict__ x,
                                                 const float* __restrict__ w,
                                                 float* __restrict__ out,
                                                 float* __restrict__ psum,
                                                 float* __restrict__ lsqp,
                                                 int* __restrict__ flat,
                                                 int* __restrict__ rnk_g,
                                                 int* __restrict__ cbe) {
  __shared__ float tile[32][68];
  __shared__ float rmv[32], invv[32], val8s[32];
  __shared__ unsigned long long Bmask[64];
  __shared__ int   fl_rows[32];
  __shared__ int   fl_n;
  __shared__ unsigned long long candmask;
  __shared__ double cexact[64];
  const int bid  = blockIdx.x;
  const int tid  = threadIdx.x;
  const int wv   = tid >> 6;
  const int lane = tid & 63;
  const int t0   = bid * 32;
  if (tid == 0) fl_n = 0;

  {
    const size_t boff = (size_t)bid * 2048;
#pragma unroll
    for (int k = 0; k < 8; ++k) {
      int idx = k * 256 + tid;
      tile[idx >> 6][idx & 63] = lg[boff + idx];
    }
  }
  __syncthreads();

  if (wv == 1) {
    float l2 = 0.0f;
    if (lane < 32) {
      const int r = lane;
      float rm = -3.0e38f;
#pragma unroll
      for (int c4 = 0; c4 < 16; ++c4) {
        float4 f = *(float4*)&tile[r][c4 * 4];
        rm = fmaxf(rm, fmaxf(fmaxf(f.x, f.y), fmaxf(f.z, f.w)));
      }
      float se = 0.0f;
#pragma unroll
      for (int c4 = 0; c4 < 16; ++c4) {
        float4 f = *(float4*)&tile[r][c4 * 4];
        se += expf(f.x - rm) + expf(f.y - rm) + expf(f.z - rm) + expf(f.w - rm);
      }
      rmv[r] = rm; invv[r] = 1.0f / se;
      float lse = rm + logf(se);
      l2 = lse * lse;
    }
#pragma unroll
    for (int o = 32; o > 0; o >>= 1) l2 += __shfl_down(l2, o);
    if (lane == 0) lsqp[bid] = l2;
  }
  __syncthreads();

  unsigned long long chosen = 0ull;   // wave-0 lane r (<32): row r's expert mask
  int myidx[8] = {0,0,0,0,0,0,0,0};
  if (wv == 0 && lane < 32) {
    const unsigned t = t0 + lane;
    float val[9]; int idx[9];
#pragma unroll
    for (int j = 0; j < 9; ++j) { val[j] = -3.0e38f; idx[j] = 0; }
    bool flag = false;
#pragma unroll
    for (int c4 = 0; c4 < 16; ++c4) {
      float4 f = *(float4*)&tile[lane][c4 * 4];
      float fe[4] = {f.x, f.y, f.z, f.w};
#pragma unroll
      for (int jj = 0; jj < 4; ++jj) {
        float v = fe[jj];
        flag = flag || (fabsf(fabsf(v) - 2.0f) < EPS);
        float c = fminf(fmaxf(v, -2.0f), 2.0f);
        int id = c4 * 4 + jj;
#pragma unroll
        for (int j = 0; j < 9; ++j) {
          bool sw = c > val[j];
          float tv = sw ? val[j] : c; int ti = sw ? idx[j] : id;
          val[j] = sw ? c : val[j];   idx[j] = sw ? id : idx[j];
          c = tv; id = ti;
        }
      }
    }
    val8s[lane] = val[8];
#pragma unroll
    for (int j = 0; j < 8; ++j) {
      float gap = val[j] - val[j + 1];
      bool bothclip = (val[j] == val[j + 1]) && (fabsf(val[j]) == 2.0f);
      flag = flag || (gap < EPS && !bothclip);
    }
    if (!flag) {
      float m = val[0], pe[8], sum = 0.0f;
#pragma unroll
      for (int j = 0; j < 8; ++j) { pe[j] = expf(val[j] - m); sum += pe[j]; }
      float inv = 1.0f / sum;
      *(float4*)&out[O_PROBS + (size_t)t * 8]     = make_float4(pe[0]*inv, pe[1]*inv, pe[2]*inv, pe[3]*inv);
      *(float4*)&out[O_PROBS + (size_t)t * 8 + 4] = make_float4(pe[4]*inv, pe[5]*inv, pe[6]*inv, pe[7]*inv);
      *(float4*)&out[O_TIDX + (size_t)t * 8]      = make_float4((float)idx[0], (float)idx[1], (float)idx[2], (float)idx[3]);
      *(float4*)&out[O_TIDX + (size_t)t * 8 + 4]  = make_float4((float)idx[4], (float)idx[5], (float)idx[6], (float)idx[7]);
      *(int4*)&flat[(size_t)t * 8]     = make_int4(idx[0], idx[1], idx[2], idx[3]);
      *(int4*)&flat[(size_t)t * 8 + 4] = make_int4(idx[4], idx[5], idx[6], idx[7]);
#pragma unroll
      for (int j = 0; j < 8; ++j) { myidx[j] = idx[j]; chosen |= 1ull << idx[j]; }
    } else {
      int sl = atomicAdd(&fl_n, 1);
      fl_rows[sl] = lane;
    }
  } else if (wv == 2 || wv == 3) {
    const int e = lane, half = wv - 2;
    float s = 0.0f;
#pragma unroll
    for (int r = 0; r < 16; ++r) {
      int rr = half * 16 + r;
      s += expf(tile[rr][e] - rmv[rr]) * invv[rr];
    }
    psum[(size_t)bid * 128 + half * 64 + e] = s;
  }
  __syncthreads();

  // ---- in-block repair (candidate-limited exact f64), rows < 32 ----
  for (int i = 0; i < fl_n; ++i) {
    const int r = fl_rows[i];
    if (wv == 0) {
      float c = fminf(fmaxf(tile[r][lane], -2.0f), 2.0f);
      bool cnd = (c >= val8s[r] - 3.0f * EPS);
      unsigned long long m = __ballot(cnd);
      if (lane == 0) candmask = m;
    }
    __syncthreads();
    const unsigned long long m = candmask;
    const float* xr = x + (size_t)(t0 + r) * HID;
    {
      int ord = 0;
      for (int e = 0; e < 64; ++e) {
        if ((m >> e) & 1ull) {
          if ((ord & 3) == wv) {
            const float* wr = w + (size_t)e * HID;
            double p0 = 0.0, p1 = 0.0, p2 = 0.0, p3 = 0.0;
            const int kb = lane * 64;
            for (int k = kb; k < kb + 64; k += 4) {
              float4 xv = *(const float4*)&xr[k];
              float4 wv4 = *(const float4*)&wr[k];
              p0 = fma((double)xv.x, (double)wv4.x, p0);
              p1 = fma((double)xv.y, (double)wv4.y, p1);
              p2 = fma((double)xv.z, (double)wv4.z, p2);
              p3 = fma((double)xv.w, (double)wv4.w, p3);
            }
            double p = (p0 + p1) + (p2 + p3);
#pragma unroll
            for (int o = 32; o > 0; o >>= 1) p += __shfl_down(p, o);
            if (lane == 0) cexact[e] = fmin(fmax(p, -2.0), 2.0);
          }
          ord++;
        }
      }
    }
    __syncthreads();
    if (tid == r) {   // wave-0 lane r
      double val[8]; int idx[8];
#pragma unroll
      for (int j = 0; j < 8; ++j) { val[j] = -1.0e300; idx[j] = 0; }
      for (int e = 0; e < 64; ++e) {
        if (!((m >> e) & 1ull)) continue;
        double c = cexact[e];
        int id = e;
#pragma unroll
        for (int j = 0; j < 8; ++j) {
          bool sw = c > val[j];
          double tv = sw ? val[j] : c; int ti = sw ? idx[j] : id;
          val[j] = sw ? c : val[j];    idx[j] = sw ? id : idx[j];
          c = tv; id = ti;
        }
      }
      float mm = (float)val[0], pe[8], sum = 0.0f;
#pragma unroll
      for (int j = 0; j < 8; ++j) { pe[j] = expf((float)val[j] - mm); sum += pe[j]; }
      float inv = 1.0f / sum;
      const unsigned t = t0 + r;
      chosen = 0ull;
#pragma unroll
      for (int j = 0; j < 8; ++j) {
        out[O_PROBS + (size_t)t * 8 + j] = pe[j] * inv;
        out[O_TIDX  + (size_t)t * 8 + j] = (float)idx[j];
        flat[(size_t)t * 8 + j] = idx[j];
        myidx[j] = idx[j];
        chosen |= 1ull << idx[j];
      }
    }
    __syncthreads();
  }

  // ---- ballot ranks + per-block counts (wave 0; rows in lanes 0..31) ----
  if (wv == 0) {
    for (int e = 0; e < 64; ++e) {
      unsigned long long b = __ballot((chosen >> e) & 1ull);
      if (lane == 0) Bmask[e] = b;
    }
    __builtin_amdgcn_wave_barrier();
    if (lane < 32) {
      const unsigned long long below = (lane == 0) ? 0ull : (~0ull >> (64 - lane));
      int rr[8];
#pragma unroll
      for (int j = 0; j < 8; ++j)
        rr[j] = (int)__popcll(Bmask[myidx[j]] & below);
      *(int4*)&rnk_g[(size_t)bid * 256 + lane * 8]     = make_int4(rr[0], rr[1], rr[2], rr[3]);
      *(int4*)&rnk_g[(size_t)bid * 256 + lane * 8 + 4] = make_int4(rr[4], rr[5], rr[6], rr[7]);
    }
    cbe[bid * 64 + lane] = (int)__popcll(Bmask[lane]);
  }
}

// ---------------------------------------------------------------------------
// Per-expert parallel scan: 64 blocks (block = expert e) x 256 thr.
// Inclusive shuffle+LDS scan over the 512 block-counts -> pref (within-expert
// exclusive prefix); also tpe[e] and psum column total pst[e].
__global__ __launch_bounds__(256) void k_scan(const int* __restrict__ cbe,
                                              const float* __restrict__ psum,
                                              int* __restrict__ pref,
                                              int* __restrict__ tpe_g,
                                              float* __restrict__ pst_g) {
  __shared__ int   wsum[4];
  __shared__ float fsum[4];
  const int e = blockIdx.x;
  const int tid = threadIdx.x;
  const int wv = tid >> 6, lane = tid & 63;

  const int c0 = cbe[(2 * tid) * 64 + e];
  const int c1 = cbe[(2 * tid + 1) * 64 + e];
  const int s = c0 + c1;

  int incl = s;
#pragma unroll
  for (int o = 1; o < 64; o <<= 1) {
    int n = __shfl_up(incl, o);
    if (lane >= o) incl += n;
  }
  if (lane == 63) wsum[wv] = incl;
  __syncthreads();
  int add = 0;
#pragma unroll
  for (int i = 0; i < 4; ++i) add += (i < wv) ? wsum[i] : 0;
  incl += add;
  const int excl = incl - s;
  pref[(2 * tid) * 64 + e]     = excl;
  pref[(2 * tid + 1) * 64 + e] = excl + c0;
  if (tid == 255) tpe_g[e] = incl;

  // expert-e probsum total
  float p = psum[(size_t)(2 * tid) * 128 + e]     + psum[(size_t)(2 * tid) * 128 + 64 + e]
          + psum[(size_t)(2 * tid + 1) * 128 + e] + psum[(size_t)(2 * tid + 1) * 128 + 64 + e];
#pragma unroll
  for (int o = 32; o > 0; o >>= 1) p += __shfl_down(p, o);
  if (lane == 0) fsum[wv] = p;
  __syncthreads();
  if (tid == 0) pst_g[e] = (fsum[0] + fsum[1]) + (fsum[2] + fsum[3]);
}

// ---------------------------------------------------------------------------
// Finalize: expert cumsum -> group/tpe/ebase; lb-loss; z-loss. 1 block.
__global__ __launch_bounds__(256) void k_fin(const int* __restrict__ tpe_g,
                                             const float* __restrict__ pst_g,
                                             const float* __restrict__ lsqp,
                                             int* __restrict__ ebase,
                                             float* __restrict__ out) {
  __shared__ float zbuf[4];
  const int tid = threadIdx.x;
  const int wv = tid >> 6, lane = tid & 63;

  // z-loss: 512 partials, 2 per thread
  float z = lsqp[tid] + lsqp[256 + tid];
#pragma unroll
  for (int o = 32; o > 0; o >>= 1) z += __shfl_down(z, o);
  if (lane == 0) zbuf[wv] = z;
  __syncthreads();
  if (tid == 0) out[O_ZL] = ((zbuf[0] + zbuf[1]) + (zbuf[2] + zbuf[3])) / 16384.0f;

  if (tid < 64) {
    int incl = 0;
    for (int i = 0; i <= tid; ++i) incl += tpe_g[i];
    const int tpe = tpe_g[tid];
    out[O_TPE + tid]   = (float)tpe;
    out[O_GROUP + tid] = (float)incl;
    ebase[tid] = incl - tpe;
    float term = ((float)tpe / 131072.0f) * (pst_g[tid] / 16384.0f) * 64.0f;
#pragma unroll
    for (int o = 32; o > 0; o >>= 1) term += __shfl_down(term, o);
    if (tid == 0) out[O_LB] = term;
  }
}

// ---------------------------------------------------------------------------
// Elementwise scatter: pos = ebase[e] + pref[block][e] + rank.
__global__ __launch_bounds__(256) void k_scatter(const int* __restrict__ flat,
                                                 const int* __restrict__ rnk,
                                                 const int* __restrict__ pref,
                                                 const int* __restrict__ ebase,
                                                 float* __restrict__ out) {
  const int j = blockIdx.x * 256 + threadIdx.x;
  const int e = flat[j];
  const int pos = ebase[e] + pref[(j >> 8) * 64 + e] + rnk[j];
  out[O_IDX + pos] = (float)j;
}

// ---------------------------------------------------------------------------
extern "C" void kernel_launch(void* const* d_in, const int* in_sizes, int n_in,
                              void* d_out, int out_size, void* d_ws, size_t ws_size,
                              hipStream_t stream) {
  (void)in_sizes; (void)n_in; (void)out_size; (void)ws_size;
  const float* x  = (const float*)d_in[0];
  const float* Wm = (const float*)d_in[1];
  float* out = (float*)d_out;
  char*  ws  = (char*)d_ws;

  float*  lsqp   = (float*)(ws + W_LSQP);
  int*    tpe_g  = (int*)(ws + W_TPE);
  float*  pst_g  = (float*)(ws + W_PST);
  int*    ebase  = (int*)(ws + W_EBASE);
  int*    cbe    = (int*)(ws + W_CBE);
  int*    pref   = (int*)(ws + W_PREF);
  float*  psum   = (float*)(ws + W_PSUM);
  int*    flat   = (int*)(ws + W_FLAT);
  int*    rnk    = (int*)(ws + W_RNK);
  short8* wf     = (short8*)(ws + W_WF);
  float*  part   = (float*)(ws + W_PART);

  k_prep   <<<dim3(128),  dim3(256), 0, stream>>>(Wm, wf);
  k_gemm   <<<dim3(NTOK / 64, NSPLIT), dim3(256), 0, stream>>>(x, wf, part);
  k_reduce <<<dim3(1024), dim3(256), 0, stream>>>(part, out + O_LOGITS);
  k_rowwise<<<dim3(RB),   dim3(256), 0, stream>>>(out + O_LOGITS, x, Wm, out, psum, lsqp, flat, rnk, cbe);
  k_scan   <<<dim3(64),   dim3(256), 0, stream>>>(cbe, psum, pref, tpe_g, pst_g);
  k_fin    <<<dim3(1),    dim3(256), 0, stream>>>(tpe_g, pst_g, lsqp, ebase, out);
  k_scatter<<<dim3(512),  dim3(256), 0, stream>>>(flat, rnk, pref, ebase, out);
}

// Round 21
// 141.235 us; speedup vs baseline: 1.0727x; 1.0727x over previous
//
#include <hip/hip_runtime.h>
#include <hip/hip_bf16.h>
#include <math.h>

#define NTOK   16384
#define NEXP   64
#define HID    4096
#define KSEL   8
#define EPS    7.5e-5f
#define NSPLIT 4
#define KSZ    (HID / NSPLIT)

typedef __attribute__((ext_vector_type(8))) short short8;
typedef __attribute__((ext_vector_type(4))) float f32x4;

// d_out element offsets (f32 elements; int outputs stored as float values)
#define O_LOGITS 0u
#define O_PROBS  1048576u
#define O_TIDX   1179648u
#define O_GROUP  1310720u
#define O_IDX    1310784u
#define O_TPE    1441856u
#define O_LB     1441920u
#define O_ZL     1441921u

// ws byte offsets
#define W_LSQP    4096u       // 256 f32 per-block z-loss partials
#define W_CBE     8192u       // 256*64 int per-block expert counts
#define W_PREF    73728u      // 256*64 int global scatter bases
#define W_PSUM    262144u     // 256*128 f32 per-block half-tile probsum partials
#define W_FLAT    524288u     // 131072 int final expert ids
#define W_RNK     1048576u    // 131072 int within-block stable ranks
#define W_WF      2097152u    // 1 MB: W packed as MFMA B-frags bf16 hi/lo
#define W_PART    4194304u    // NSPLIT x 4 MB f32 partials
#define PART_STRIDE 1048576ull

// round-to-nearest-even f32 -> bf16 bits
__device__ __forceinline__ unsigned short f2bf(float f) {
  unsigned u = __float_as_uint(f);
  return (unsigned short)((u + 0x7fffu + ((u >> 16) & 1u)) >> 16);
}

__device__ __forceinline__ void gload16(const void* g, void* l) {
  __builtin_amdgcn_global_load_lds((const __attribute__((address_space(1))) unsigned int*)g,
                                   (__attribute__((address_space(3))) unsigned int*)l, 16, 0, 0);
}

// ---------------------------------------------------------------------------
// prep: pack W into MFMA B-frags (bf16 hi/lo).
__global__ __launch_bounds__(256) void k_prep(const float* __restrict__ w,
                                              short8* __restrict__ wf) {
  const int kk   = blockIdx.x;
  const int nb   = threadIdx.x >> 6;
  const int lane = threadIdx.x & 63;
  const int n    = nb * 16 + (lane & 15);
  const int kb   = kk * 32 + (lane >> 4) * 8;
  const float4* wp = (const float4*)(w + (size_t)n * HID + kb);
  float4 f0 = wp[0], f1 = wp[1];
  float fv[8] = {f0.x, f0.y, f0.z, f0.w, f1.x, f1.y, f1.z, f1.w};
  short8 hi, lo;
#pragma unroll
  for (int j = 0; j < 8; ++j) {
    unsigned short h = f2bf(fv[j]);
    hi[j] = (short)h;
    float r = fv[j] - __uint_as_float((unsigned)h << 16);
    lo[j] = (short)f2bf(r);
  }
  size_t base = ((size_t)(kk * 4 + nb) * 2) * 64 + lane;
  wf[base] = hi;
  wf[base + 64] = lo;
}

// ---------------------------------------------------------------------------
// MFMA router GEMM (R8-exact, measured ~56us).
__global__ __launch_bounds__(256, 4) void k_gemm(const float* __restrict__ x,
                                                 const short8* __restrict__ wf,
                                                 float* __restrict__ part) {
  __shared__ short8 wl[2][512];   // 2 x 8 KB
  const int tid  = threadIdx.x;
  const int wv   = tid >> 6;
  const int lane = tid & 63;
  const int t0   = blockIdx.x * 64;
  const int k0   = blockIdx.y * KSZ;
  const int row  = t0 + wv * 16 + (lane & 15);

  const float* xp = x + (size_t)row * HID + k0 + (lane >> 4) * 8;
  const short8* wbase = wf + (size_t)(k0 >> 5) * 512;

  auto stage = [&](int c, int b) {
    const short8* src = wbase + (size_t)c * 512;
#pragma unroll
    for (int r = 0; r < 2; ++r) {
      const int o = r * 256 + wv * 64;       // wave-uniform LDS base
      gload16(src + o + lane, &wl[b][o]);    // lane*16B added by HW
    }
  };

  f32x4 acc[4] = {{0,0,0,0},{0,0,0,0},{0,0,0,0},{0,0,0,0}};

  stage(0, 0);
  __syncthreads();
  const int nch = KSZ >> 5;   // 32
  for (int c = 0; c < nch; ++c) {
    const int b = c & 1;
    if (c + 1 < nch) stage(c + 1, b ^ 1);

    const float4* xq = (const float4*)(xp + c * 32);
    float4 f0 = xq[0], f1 = xq[1];
    unsigned xb[8] = {__float_as_uint(f0.x), __float_as_uint(f0.y),
                      __float_as_uint(f0.z), __float_as_uint(f0.w),
                      __float_as_uint(f1.x), __float_as_uint(f1.y),
                      __float_as_uint(f1.z), __float_as_uint(f1.w)};
    union { unsigned u[4]; short8 s; } ua, ul;
#pragma unroll
    for (int p = 0; p < 4; ++p) {
      unsigned b0 = xb[2 * p], b1 = xb[2 * p + 1];
      ua.u[p] = __builtin_amdgcn_perm(b1, b0, 0x07060302u);
      float r0 = __uint_as_float(b0) - __uint_as_float(b0 & 0xffff0000u);
      float r1 = __uint_as_float(b1) - __uint_as_float(b1 & 0xffff0000u);
      unsigned t0b = __float_as_uint(r0), t1b = __float_as_uint(r1);
      t0b += 0x7fffu + ((t0b >> 16) & 1u);
      t1b += 0x7fffu + ((t1b >> 16) & 1u);
      ul.u[p] = __builtin_amdgcn_perm(t1b, t0b, 0x07060302u);
    }
    short8 ah = ua.s, al = ul.s;

#pragma unroll
    for (int nb = 0; nb < 4; ++nb) {
      short8 bh = wl[b][nb * 128 + lane];
      short8 bl = wl[b][nb * 128 + 64 + lane];
      acc[nb] = __builtin_amdgcn_mfma_f32_16x16x32_bf16(ah, bh, acc[nb], 0, 0, 0);
      acc[nb] = __builtin_amdgcn_mfma_f32_16x16x32_bf16(al, bh, acc[nb], 0, 0, 0);
      acc[nb] = __builtin_amdgcn_mfma_f32_16x16x32_bf16(ah, bl, acc[nb], 0, 0, 0);
    }
    __syncthreads();
  }

  float* p = part + (size_t)blockIdx.y * PART_STRIDE;
  const int mrow = t0 + wv * 16 + (lane >> 4) * 4;
  const int col  = lane & 15;
#pragma unroll
  for (int nb = 0; nb < 4; ++nb)
#pragma unroll
    for (int r = 0; r < 4; ++r)
      p[(size_t)(mrow + r) * 64 + nb * 16 + col] = acc[nb][r];
}

// ---------------------------------------------------------------------------
// Split-K reduce, 1024 blocks (R3-proven).
__global__ __launch_bounds__(256) void k_reduce(const float* __restrict__ part,
                                                float* __restrict__ out_logits) {
  unsigned i4 = blockIdx.x * 256u + threadIdx.x;
  const float4* p4 = (const float4*)part;
  float4 v = p4[i4];
#pragma unroll
  for (int s = 1; s < NSPLIT; ++s) {
    float4 a = p4[(size_t)s * (PART_STRIDE / 4) + i4];
    v.x += a.x; v.y += a.y; v.z += a.z; v.w += a.w;
  }
  ((float4*)out_logits)[i4] = v;
}

// ---------------------------------------------------------------------------
// Rowwise + in-block repair + ballot-based stable ranks (R19-exact structure;
// expf/logf -> __expf/__logf: exp appears only AFTER all discrete decisions,
// so topk/flags/ranks are bit-identical; probs/losses shift ~1e-6 vs 2% thr).
__global__ __launch_bounds__(256) void k_rowwise(const float* __restrict__ lg,
                                                 const float* __restrict__ x,
                                                 const float* __restrict__ w,
                                                 float* __restrict__ out,
                                                 float* __restrict__ psum,
                                                 float* __restrict__ lsqp,
                                                 int* __restrict__ flat,
                                                 int* __restrict__ rnk_g,
                                                 int* __restrict__ cbe) {
  __shared__ float tile[64][68];
  __shared__ float rmv[64], invv[64], val8s[64];
  __shared__ unsigned long long Bmask[64];
  __shared__ int   fl_rows[64];
  __shared__ int   fl_n;
  __shared__ unsigned long long candmask;
  __shared__ double cexact[64];
  const int bid  = blockIdx.x;
  const int tid  = threadIdx.x;
  const int wv   = tid >> 6;
  const int lane = tid & 63;
  const int t0   = bid * 64;
  if (tid == 0) fl_n = 0;

  {
    const size_t boff = (size_t)bid * 4096;
#pragma unroll
    for (int k = 0; k < 16; ++k) {
      int idx = k * 256 + tid;
      tile[idx >> 6][idx & 63] = lg[boff + idx];
    }
  }
  __syncthreads();

  if (wv == 1) {
    const int r = lane;
    float rm = -3.0e38f;
#pragma unroll
    for (int c4 = 0; c4 < 16; ++c4) {
      float4 f = *(float4*)&tile[r][c4 * 4];
      rm = fmaxf(rm, fmaxf(fmaxf(f.x, f.y), fmaxf(f.z, f.w)));
    }
    float se = 0.0f;
#pragma unroll
    for (int c4 = 0; c4 < 16; ++c4) {
      float4 f = *(float4*)&tile[r][c4 * 4];
      se += __expf(f.x - rm) + __expf(f.y - rm) + __expf(f.z - rm) + __expf(f.w - rm);
    }
    rmv[r] = rm; invv[r] = 1.0f / se;
    float lse = rm + __logf(se);
    float l2 = lse * lse;
#pragma unroll
    for (int o = 32; o > 0; o >>= 1) l2 += __shfl_down(l2, o);
    if (lane == 0) lsqp[bid] = l2;
  }
  __syncthreads();

  unsigned long long chosen = 0ull;   // wave-0 lane r: bitmask of row r's experts
  int myidx[8] = {0,0,0,0,0,0,0,0};
  if (wv == 0) {
    const unsigned t = t0 + lane;
    float val[9]; int idx[9];
#pragma unroll
    for (int j = 0; j < 9; ++j) { val[j] = -3.0e38f; idx[j] = 0; }
    bool flag = false;
#pragma unroll
    for (int c4 = 0; c4 < 16; ++c4) {
      float4 f = *(float4*)&tile[lane][c4 * 4];
      float fe[4] = {f.x, f.y, f.z, f.w};
#pragma unroll
      for (int jj = 0; jj < 4; ++jj) {
        float v = fe[jj];
        flag = flag || (fabsf(fabsf(v) - 2.0f) < EPS);
        float c = fminf(fmaxf(v, -2.0f), 2.0f);
        int id = c4 * 4 + jj;
#pragma unroll
        for (int j = 0; j < 9; ++j) {
          bool sw = c > val[j];
          float tv = sw ? val[j] : c; int ti = sw ? idx[j] : id;
          val[j] = sw ? c : val[j];   idx[j] = sw ? id : idx[j];
          c = tv; id = ti;
        }
      }
    }
    val8s[lane] = val[8];
#pragma unroll
    for (int j = 0; j < 8; ++j) {
      float gap = val[j] - val[j + 1];
      bool bothclip = (val[j] == val[j + 1]) && (fabsf(val[j]) == 2.0f);
      flag = flag || (gap < EPS && !bothclip);
    }
    if (!flag) {
      float m = val[0], pe[8], sum = 0.0f;
#pragma unroll
      for (int j = 0; j < 8; ++j) { pe[j] = __expf(val[j] - m); sum += pe[j]; }
      float inv = 1.0f / sum;
      *(float4*)&out[O_PROBS + (size_t)t * 8]     = make_float4(pe[0]*inv, pe[1]*inv, pe[2]*inv, pe[3]*inv);
      *(float4*)&out[O_PROBS + (size_t)t * 8 + 4] = make_float4(pe[4]*inv, pe[5]*inv, pe[6]*inv, pe[7]*inv);
      *(float4*)&out[O_TIDX + (size_t)t * 8]      = make_float4((float)idx[0], (float)idx[1], (float)idx[2], (float)idx[3]);
      *(float4*)&out[O_TIDX + (size_t)t * 8 + 4]  = make_float4((float)idx[4], (float)idx[5], (float)idx[6], (float)idx[7]);
      *(int4*)&flat[(size_t)t * 8]     = make_int4(idx[0], idx[1], idx[2], idx[3]);
      *(int4*)&flat[(size_t)t * 8 + 4] = make_int4(idx[4], idx[5], idx[6], idx[7]);
#pragma unroll
      for (int j = 0; j < 8; ++j) { myidx[j] = idx[j]; chosen |= 1ull << idx[j]; }
    } else {
      int sl = atomicAdd(&fl_n, 1);
      fl_rows[sl] = lane;
    }
  } else if (wv == 2 || wv == 3) {
    const int e = lane, half = wv - 2;
    float s = 0.0f;
#pragma unroll
    for (int r = 0; r < 32; ++r) {
      int rr = half * 32 + r;
      s += __expf(tile[rr][e] - rmv[rr]) * invv[rr];
    }
    psum[(size_t)bid * 128 + half * 64 + e] = s;
  }
  __syncthreads();

  // ---- in-block repair of flagged rows (candidate-limited exact f64) ----
  for (int i = 0; i < fl_n; ++i) {
    const int r = fl_rows[i];
    if (wv == 0) {
      float c = fminf(fmaxf(tile[r][lane], -2.0f), 2.0f);
      bool cnd = (c >= val8s[r] - 3.0f * EPS);
      unsigned long long m = __ballot(cnd);
      if (lane == 0) candmask = m;
    }
    __syncthreads();
    const unsigned long long m = candmask;
    const float* xr = x + (size_t)(t0 + r) * HID;
    {
      int ord = 0;
      for (int e = 0; e < 64; ++e) {
        if ((m >> e) & 1ull) {
          if ((ord & 3) == wv) {
            const float* wr = w + (size_t)e * HID;
            double p0 = 0.0, p1 = 0.0, p2 = 0.0, p3 = 0.0;
            const int kb = lane * 64;
            for (int k = kb; k < kb + 64; k += 4) {
              float4 xv = *(const float4*)&xr[k];
              float4 wv4 = *(const float4*)&wr[k];
              p0 = fma((double)xv.x, (double)wv4.x, p0);
              p1 = fma((double)xv.y, (double)wv4.y, p1);
              p2 = fma((double)xv.z, (double)wv4.z, p2);
              p3 = fma((double)xv.w, (double)wv4.w, p3);
            }
            double p = (p0 + p1) + (p2 + p3);
#pragma unroll
            for (int o = 32; o > 0; o >>= 1) p += __shfl_down(p, o);
            if (lane == 0) cexact[e] = fmin(fmax(p, -2.0), 2.0);
          }
          ord++;
        }
      }
    }
    __syncthreads();
    if (tid == r) {   // wave-0 lane r
      double val[8]; int idx[8];
#pragma unroll
      for (int j = 0; j < 8; ++j) { val[j] = -1.0e300; idx[j] = 0; }
      for (int e = 0; e < 64; ++e) {
        if (!((m >> e) & 1ull)) continue;
        double c = cexact[e];
        int id = e;
#pragma unroll
        for (int j = 0; j < 8; ++j) {
          bool sw = c > val[j];
          double tv = sw ? val[j] : c; int ti = sw ? idx[j] : id;
          val[j] = sw ? c : val[j];    idx[j] = sw ? id : idx[j];
          c = tv; id = ti;
        }
      }
      float mm = (float)val[0], pe[8], sum = 0.0f;
#pragma unroll
      for (int j = 0; j < 8; ++j) { pe[j] = __expf((float)val[j] - mm); sum += pe[j]; }
      float inv = 1.0f / sum;
      const unsigned t = t0 + r;
      chosen = 0ull;
#pragma unroll
      for (int j = 0; j < 8; ++j) {
        out[O_PROBS + (size_t)t * 8 + j] = pe[j] * inv;
        out[O_TIDX  + (size_t)t * 8 + j] = (float)idx[j];
        flat[(size_t)t * 8 + j] = idx[j];
        myidx[j] = idx[j];
        chosen |= 1ull << idx[j];
      }
    }
    __syncthreads();
  }

  // ---- ballot-based ranks + counts (wave 0 only; 64 ballots, O(1) depth) ----
  if (wv == 0) {
    for (int e = 0; e < 64; ++e) {
      unsigned long long b = __ballot((chosen >> e) & 1ull);
      if (lane == 0) Bmask[e] = b;
    }
    __builtin_amdgcn_wave_barrier();
    const unsigned long long below = (lane == 0) ? 0ull : (~0ull >> (64 - lane));
    int rr[8];
#pragma unroll
    for (int j = 0; j < 8; ++j)
      rr[j] = (int)__popcll(Bmask[myidx[j]] & below);
    *(int4*)&rnk_g[(size_t)bid * 512 + lane * 8]     = make_int4(rr[0], rr[1], rr[2], rr[3]);
    *(int4*)&rnk_g[(size_t)bid * 512 + lane * 8 + 4] = make_int4(rr[4], rr[5], rr[6], rr[7]);
    cbe[bid * 64 + lane] = (int)__popcll(Bmask[lane]);
  }
}

// ---------------------------------------------------------------------------
// Scan + finalize, segmented (R19-exact). 1 block x 256 thr.
__global__ __launch_bounds__(256) void k_scan(const int* __restrict__ cbe,
                                              const float* __restrict__ psum,
                                              const float* __restrict__ lsqp,
                                              int* __restrict__ pref,
                                              float* __restrict__ out) {
  __shared__ int part4[4][64];
  __shared__ int segb[4][64];
  __shared__ int ctot[64];
  __shared__ float gsum[4][64];
  const int tid = threadIdx.x;
  const int e = tid & 63, g = tid >> 6;

  float ps = 0.0f;
  int cs = 0;
  for (int b = g * 64; b < g * 64 + 64; ++b) {
    ps += psum[(size_t)b * 128 + e] + psum[(size_t)b * 128 + 64 + e];
    cs += cbe[b * 64 + e];
  }
  gsum[g][e] = ps;
  part4[g][e] = cs;
  __syncthreads();

  if (tid < 64) {
    ctot[tid] = part4[0][tid] + part4[1][tid] + part4[2][tid] + part4[3][tid];
  }
  __syncthreads();

  if (tid < 64) {
    int incl = 0;
    for (int i = 0; i <= tid; ++i) incl += ctot[i];
    const int tpe = ctot[tid];
    out[O_TPE + tid]   = (float)tpe;
    out[O_GROUP + tid] = (float)incl;
    int base = incl - tpe;
    for (int gg = 0; gg < 4; ++gg) { segb[gg][tid] = base; base += part4[gg][tid]; }

    float pst = (gsum[0][tid] + gsum[1][tid]) + (gsum[2][tid] + gsum[3][tid]);
    float term = ((float)tpe / 131072.0f) * (pst / 16384.0f) * 64.0f;
#pragma unroll
    for (int o2 = 32; o2 > 0; o2 >>= 1) term += __shfl_down(term, o2);
    float zs = (lsqp[tid * 4] + lsqp[tid * 4 + 1]) + (lsqp[tid * 4 + 2] + lsqp[tid * 4 + 3]);
#pragma unroll
    for (int o2 = 32; o2 > 0; o2 >>= 1) zs += __shfl_down(zs, o2);
    if (tid == 0) { out[O_LB] = term; out[O_ZL] = zs / 16384.0f; }
  }
  __syncthreads();

  int run = segb[g][e];
  for (int b = g * 64; b < g * 64 + 64; ++b) {
    pref[b * 64 + e] = run;
    run += cbe[b * 64 + e];
  }
}

// ---------------------------------------------------------------------------
// Elementwise scatter: pos = pref[block][e] + rank. 512 blocks x 256 thr.
__global__ __launch_bounds__(256) void k_scatter(const int* __restrict__ flat,
                                                 const int* __restrict__ rnk,
                                                 const int* __restrict__ pref,
                                                 float* __restrict__ out) {
  const int j = blockIdx.x * 256 + threadIdx.x;
  const int e = flat[j];
  const int pos = pref[(j >> 9) * 64 + e] + rnk[j];
  out[O_IDX + pos] = (float)j;
}

// ---------------------------------------------------------------------------
extern "C" void kernel_launch(void* const* d_in, const int* in_sizes, int n_in,
                              void* d_out, int out_size, void* d_ws, size_t ws_size,
                              hipStream_t stream) {
  (void)in_sizes; (void)n_in; (void)out_size; (void)ws_size;
  const float* x  = (const float*)d_in[0];
  const float* Wm = (const float*)d_in[1];
  float* out = (float*)d_out;
  char*  ws  = (char*)d_ws;

  float*  lsqp   = (float*)(ws + W_LSQP);
  int*    cbe    = (int*)(ws + W_CBE);
  int*    pref   = (int*)(ws + W_PREF);
  float*  psum   = (float*)(ws + W_PSUM);
  int*    flat   = (int*)(ws + W_FLAT);
  int*    rnk    = (int*)(ws + W_RNK);
  short8* wf     = (short8*)(ws + W_WF);
  float*  part   = (float*)(ws + W_PART);

  k_prep   <<<dim3(128),  dim3(256), 0, stream>>>(Wm, wf);
  k_gemm   <<<dim3(NTOK / 64, NSPLIT), dim3(256), 0, stream>>>(x, wf, part);
  k_reduce <<<dim3(1024), dim3(256), 0, stream>>>(part, out + O_LOGITS);
  k_rowwise<<<dim3(256),  dim3(256), 0, stream>>>(out + O_LOGITS, x, Wm, out, psum, lsqp, flat, rnk, cbe);
  k_scan   <<<dim3(1),    dim3(256), 0, stream>>>(cbe, psum, lsqp, pref, out);
  k_scatter<<<dim3(512),  dim3(256), 0, stream>>>(flat, rnk, pref, out);
}

// Round 22
// 140.628 us; speedup vs baseline: 1.0773x; 1.0043x over previous
//
#include <hip/hip_runtime.h>
#include <hip/hip_bf16.h>
#include <math.h>

#define NTOK   16384
#define NEXP   64
#define HID    4096
#define KSEL   8
#define EPS    7.5e-5f
#define NSPLIT 4
#define KSZ    (HID / NSPLIT)

typedef __attribute__((ext_vector_type(8))) short short8;
typedef __attribute__((ext_vector_type(4))) float f32x4;

// d_out element offsets (f32 elements; int outputs stored as float values)
#define O_LOGITS 0u
#define O_PROBS  1048576u
#define O_TIDX   1179648u
#define O_GROUP  1310720u
#define O_IDX    1310784u
#define O_TPE    1441856u
#define O_LB     1441920u
#define O_ZL     1441921u

// ws byte offsets
#define W_LSQP    4096u       // 256 f32 per-block z-loss partials
#define W_CBE     8192u       // 256*64 int per-block expert counts
#define W_PREF    73728u      // 256*64 int within-expert block prefixes
#define W_TPE     139264u     // 64 int
#define W_PST     139520u     // 64 f32
#define W_EBASE   139776u     // 64 int
#define W_PSUM    262144u     // 256*128 f32 per-block half-tile probsum partials
#define W_FLAT    524288u     // 131072 int final expert ids
#define W_RNK     1048576u    // 131072 int within-block stable ranks
#define W_WF      2097152u    // 1 MB: W packed as MFMA B-frags bf16 hi/lo
#define W_PART    4194304u    // NSPLIT x 4 MB f32 partials
#define PART_STRIDE 1048576ull

// round-to-nearest-even f32 -> bf16 bits
__device__ __forceinline__ unsigned short f2bf(float f) {
  unsigned u = __float_as_uint(f);
  return (unsigned short)((u + 0x7fffu + ((u >> 16) & 1u)) >> 16);
}

__device__ __forceinline__ void gload16(const void* g, void* l) {
  __builtin_amdgcn_global_load_lds((const __attribute__((address_space(1))) unsigned int*)g,
                                   (__attribute__((address_space(3))) unsigned int*)l, 16, 0, 0);
}

// ---------------------------------------------------------------------------
// prep: pack W into MFMA B-frags (bf16 hi/lo).
__global__ __launch_bounds__(256) void k_prep(const float* __restrict__ w,
                                              short8* __restrict__ wf) {
  const int kk   = blockIdx.x;
  const int nb   = threadIdx.x >> 6;
  const int lane = threadIdx.x & 63;
  const int n    = nb * 16 + (lane & 15);
  const int kb   = kk * 32 + (lane >> 4) * 8;
  const float4* wp = (const float4*)(w + (size_t)n * HID + kb);
  float4 f0 = wp[0], f1 = wp[1];
  float fv[8] = {f0.x, f0.y, f0.z, f0.w, f1.x, f1.y, f1.z, f1.w};
  short8 hi, lo;
#pragma unroll
  for (int j = 0; j < 8; ++j) {
    unsigned short h = f2bf(fv[j]);
    hi[j] = (short)h;
    float r = fv[j] - __uint_as_float((unsigned)h << 16);
    lo[j] = (short)f2bf(r);
  }
  size_t base = ((size_t)(kk * 4 + nb) * 2) * 64 + lane;
  wf[base] = hi;
  wf[base + 64] = lo;
}

// ---------------------------------------------------------------------------
// MFMA router GEMM (R8-exact, measured ~56us).
__global__ __launch_bounds__(256, 4) void k_gemm(const float* __restrict__ x,
                                                 const short8* __restrict__ wf,
                                                 float* __restrict__ part) {
  __shared__ short8 wl[2][512];   // 2 x 8 KB
  const int tid  = threadIdx.x;
  const int wv   = tid >> 6;
  const int lane = tid & 63;
  const int t0   = blockIdx.x * 64;
  const int k0   = blockIdx.y * KSZ;
  const int row  = t0 + wv * 16 + (lane & 15);

  const float* xp = x + (size_t)row * HID + k0 + (lane >> 4) * 8;
  const short8* wbase = wf + (size_t)(k0 >> 5) * 512;

  auto stage = [&](int c, int b) {
    const short8* src = wbase + (size_t)c * 512;
#pragma unroll
    for (int r = 0; r < 2; ++r) {
      const int o = r * 256 + wv * 64;       // wave-uniform LDS base
      gload16(src + o + lane, &wl[b][o]);    // lane*16B added by HW
    }
  };

  f32x4 acc[4] = {{0,0,0,0},{0,0,0,0},{0,0,0,0},{0,0,0,0}};

  stage(0, 0);
  __syncthreads();
  const int nch = KSZ >> 5;   // 32
  for (int c = 0; c < nch; ++c) {
    const int b = c & 1;
    if (c + 1 < nch) stage(c + 1, b ^ 1);

    const float4* xq = (const float4*)(xp + c * 32);
    float4 f0 = xq[0], f1 = xq[1];
    unsigned xb[8] = {__float_as_uint(f0.x), __float_as_uint(f0.y),
                      __float_as_uint(f0.z), __float_as_uint(f0.w),
                      __float_as_uint(f1.x), __float_as_uint(f1.y),
                      __float_as_uint(f1.z), __float_as_uint(f1.w)};
    union { unsigned u[4]; short8 s; } ua, ul;
#pragma unroll
    for (int p = 0; p < 4; ++p) {
      unsigned b0 = xb[2 * p], b1 = xb[2 * p + 1];
      ua.u[p] = __builtin_amdgcn_perm(b1, b0, 0x07060302u);
      float r0 = __uint_as_float(b0) - __uint_as_float(b0 & 0xffff0000u);
      float r1 = __uint_as_float(b1) - __uint_as_float(b1 & 0xffff0000u);
      unsigned t0b = __float_as_uint(r0), t1b = __float_as_uint(r1);
      t0b += 0x7fffu + ((t0b >> 16) & 1u);
      t1b += 0x7fffu + ((t1b >> 16) & 1u);
      ul.u[p] = __builtin_amdgcn_perm(t1b, t0b, 0x07060302u);
    }
    short8 ah = ua.s, al = ul.s;

#pragma unroll
    for (int nb = 0; nb < 4; ++nb) {
      short8 bh = wl[b][nb * 128 + lane];
      short8 bl = wl[b][nb * 128 + 64 + lane];
      acc[nb] = __builtin_amdgcn_mfma_f32_16x16x32_bf16(ah, bh, acc[nb], 0, 0, 0);
      acc[nb] = __builtin_amdgcn_mfma_f32_16x16x32_bf16(al, bh, acc[nb], 0, 0, 0);
      acc[nb] = __builtin_amdgcn_mfma_f32_16x16x32_bf16(ah, bl, acc[nb], 0, 0, 0);
    }
    __syncthreads();
  }

  float* p = part + (size_t)blockIdx.y * PART_STRIDE;
  const int mrow = t0 + wv * 16 + (lane >> 4) * 4;
  const int col  = lane & 15;
#pragma unroll
  for (int nb = 0; nb < 4; ++nb)
#pragma unroll
    for (int r = 0; r < 4; ++r)
      p[(size_t)(mrow + r) * 64 + nb * 16 + col] = acc[nb][r];
}

// ---------------------------------------------------------------------------
// Split-K reduce, 1024 blocks (R3-proven).
__global__ __launch_bounds__(256) void k_reduce(const float* __restrict__ part,
                                                float* __restrict__ out_logits) {
  unsigned i4 = blockIdx.x * 256u + threadIdx.x;
  const float4* p4 = (const float4*)part;
  float4 v = p4[i4];
#pragma unroll
  for (int s = 1; s < NSPLIT; ++s) {
    float4 a = p4[(size_t)s * (PART_STRIDE / 4) + i4];
    v.x += a.x; v.y += a.y; v.z += a.z; v.w += a.w;
  }
  ((float4*)out_logits)[i4] = v;
}

// ---------------------------------------------------------------------------
// Rowwise + in-block repair + ballot-based stable ranks (R21-exact).
__global__ __launch_bounds__(256) void k_rowwise(const float* __restrict__ lg,
                                                 const float* __restrict__ x,
                                                 const float* __restrict__ w,
                                                 float* __restrict__ out,
                                                 float* __restrict__ psum,
                                                 float* __restrict__ lsqp,
                                                 int* __restrict__ flat,
                                                 int* __restrict__ rnk_g,
                                                 int* __restrict__ cbe) {
  __shared__ float tile[64][68];
  __shared__ float rmv[64], invv[64], val8s[64];
  __shared__ unsigned long long Bmask[64];
  __shared__ int   fl_rows[64];
  __shared__ int   fl_n;
  __shared__ unsigned long long candmask;
  __shared__ double cexact[64];
  const int bid  = blockIdx.x;
  const int tid  = threadIdx.x;
  const int wv   = tid >> 6;
  const int lane = tid & 63;
  const int t0   = bid * 64;
  if (tid == 0) fl_n = 0;

  {
    const size_t boff = (size_t)bid * 4096;
#pragma unroll
    for (int k = 0; k < 16; ++k) {
      int idx = k * 256 + tid;
      tile[idx >> 6][idx & 63] = lg[boff + idx];
    }
  }
  __syncthreads();

  if (wv == 1) {
    const int r = lane;
    float rm = -3.0e38f;
#pragma unroll
    for (int c4 = 0; c4 < 16; ++c4) {
      float4 f = *(float4*)&tile[r][c4 * 4];
      rm = fmaxf(rm, fmaxf(fmaxf(f.x, f.y), fmaxf(f.z, f.w)));
    }
    float se = 0.0f;
#pragma unroll
    for (int c4 = 0; c4 < 16; ++c4) {
      float4 f = *(float4*)&tile[r][c4 * 4];
      se += __expf(f.x - rm) + __expf(f.y - rm) + __expf(f.z - rm) + __expf(f.w - rm);
    }
    rmv[r] = rm; invv[r] = 1.0f / se;
    float lse = rm + __logf(se);
    float l2 = lse * lse;
#pragma unroll
    for (int o = 32; o > 0; o >>= 1) l2 += __shfl_down(l2, o);
    if (lane == 0) lsqp[bid] = l2;
  }
  __syncthreads();

  unsigned long long chosen = 0ull;
  int myidx[8] = {0,0,0,0,0,0,0,0};
  if (wv == 0) {
    const unsigned t = t0 + lane;
    float val[9]; int idx[9];
#pragma unroll
    for (int j = 0; j < 9; ++j) { val[j] = -3.0e38f; idx[j] = 0; }
    bool flag = false;
#pragma unroll
    for (int c4 = 0; c4 < 16; ++c4) {
      float4 f = *(float4*)&tile[lane][c4 * 4];
      float fe[4] = {f.x, f.y, f.z, f.w};
#pragma unroll
      for (int jj = 0; jj < 4; ++jj) {
        float v = fe[jj];
        flag = flag || (fabsf(fabsf(v) - 2.0f) < EPS);
        float c = fminf(fmaxf(v, -2.0f), 2.0f);
        int id = c4 * 4 + jj;
#pragma unroll
        for (int j = 0; j < 9; ++j) {
          bool sw = c > val[j];
          float tv = sw ? val[j] : c; int ti = sw ? idx[j] : id;
          val[j] = sw ? c : val[j];   idx[j] = sw ? id : idx[j];
          c = tv; id = ti;
        }
      }
    }
    val8s[lane] = val[8];
#pragma unroll
    for (int j = 0; j < 8; ++j) {
      float gap = val[j] - val[j + 1];
      bool bothclip = (val[j] == val[j + 1]) && (fabsf(val[j]) == 2.0f);
      flag = flag || (gap < EPS && !bothclip);
    }
    if (!flag) {
      float m = val[0], pe[8], sum = 0.0f;
#pragma unroll
      for (int j = 0; j < 8; ++j) { pe[j] = __expf(val[j] - m); sum += pe[j]; }
      float inv = 1.0f / sum;
      *(float4*)&out[O_PROBS + (size_t)t * 8]     = make_float4(pe[0]*inv, pe[1]*inv, pe[2]*inv, pe[3]*inv);
      *(float4*)&out[O_PROBS + (size_t)t * 8 + 4] = make_float4(pe[4]*inv, pe[5]*inv, pe[6]*inv, pe[7]*inv);
      *(float4*)&out[O_TIDX + (size_t)t * 8]      = make_float4((float)idx[0], (float)idx[1], (float)idx[2], (float)idx[3]);
      *(float4*)&out[O_TIDX + (size_t)t * 8 + 4]  = make_float4((float)idx[4], (float)idx[5], (float)idx[6], (float)idx[7]);
      *(int4*)&flat[(size_t)t * 8]     = make_int4(idx[0], idx[1], idx[2], idx[3]);
      *(int4*)&flat[(size_t)t * 8 + 4] = make_int4(idx[4], idx[5], idx[6], idx[7]);
#pragma unroll
      for (int j = 0; j < 8; ++j) { myidx[j] = idx[j]; chosen |= 1ull << idx[j]; }
    } else {
      int sl = atomicAdd(&fl_n, 1);
      fl_rows[sl] = lane;
    }
  } else if (wv == 2 || wv == 3) {
    const int e = lane, half = wv - 2;
    float s = 0.0f;
#pragma unroll
    for (int r = 0; r < 32; ++r) {
      int rr = half * 32 + r;
      s += __expf(tile[rr][e] - rmv[rr]) * invv[rr];
    }
    psum[(size_t)bid * 128 + half * 64 + e] = s;
  }
  __syncthreads();

  for (int i = 0; i < fl_n; ++i) {
    const int r = fl_rows[i];
    if (wv == 0) {
      float c = fminf(fmaxf(tile[r][lane], -2.0f), 2.0f);
      bool cnd = (c >= val8s[r] - 3.0f * EPS);
      unsigned long long m = __ballot(cnd);
      if (lane == 0) candmask = m;
    }
    __syncthreads();
    const unsigned long long m = candmask;
    const float* xr = x + (size_t)(t0 + r) * HID;
    {
      int ord = 0;
      for (int e = 0; e < 64; ++e) {
        if ((m >> e) & 1ull) {
          if ((ord & 3) == wv) {
            const float* wr = w + (size_t)e * HID;
            double p0 = 0.0, p1 = 0.0, p2 = 0.0, p3 = 0.0;
            const int kb = lane * 64;
            for (int k = kb; k < kb + 64; k += 4) {
              float4 xv = *(const float4*)&xr[k];
              float4 wv4 = *(const float4*)&wr[k];
              p0 = fma((double)xv.x, (double)wv4.x, p0);
              p1 = fma((double)xv.y, (double)wv4.y, p1);
              p2 = fma((double)xv.z, (double)wv4.z, p2);
              p3 = fma((double)xv.w, (double)wv4.w, p3);
            }
            double p = (p0 + p1) + (p2 + p3);
#pragma unroll
            for (int o = 32; o > 0; o >>= 1) p += __shfl_down(p, o);
            if (lane == 0) cexact[e] = fmin(fmax(p, -2.0), 2.0);
          }
          ord++;
        }
      }
    }
    __syncthreads();
    if (tid == r) {
      double val[8]; int idx[8];
#pragma unroll
      for (int j = 0; j < 8; ++j) { val[j] = -1.0e300; idx[j] = 0; }
      for (int e = 0; e < 64; ++e) {
        if (!((m >> e) & 1ull)) continue;
        double c = cexact[e];
        int id = e;
#pragma unroll
        for (int j = 0; j < 8; ++j) {
          bool sw = c > val[j];
          double tv = sw ? val[j] : c; int ti = sw ? idx[j] : id;
          val[j] = sw ? c : val[j];    idx[j] = sw ? id : idx[j];
          c = tv; id = ti;
        }
      }
      float mm = (float)val[0], pe[8], sum = 0.0f;
#pragma unroll
      for (int j = 0; j < 8; ++j) { pe[j] = __expf((float)val[j] - mm); sum += pe[j]; }
      float inv = 1.0f / sum;
      const unsigned t = t0 + r;
      chosen = 0ull;
#pragma unroll
      for (int j = 0; j < 8; ++j) {
        out[O_PROBS + (size_t)t * 8 + j] = pe[j] * inv;
        out[O_TIDX  + (size_t)t * 8 + j] = (float)idx[j];
        flat[(size_t)t * 8 + j] = idx[j];
        myidx[j] = idx[j];
        chosen |= 1ull << idx[j];
      }
    }
    __syncthreads();
  }

  if (wv == 0) {
    for (int e = 0; e < 64; ++e) {
      unsigned long long b = __ballot((chosen >> e) & 1ull);
      if (lane == 0) Bmask[e] = b;
    }
    __builtin_amdgcn_wave_barrier();
    const unsigned long long below = (lane == 0) ? 0ull : (~0ull >> (64 - lane));
    int rr[8];
#pragma unroll
    for (int j = 0; j < 8; ++j)
      rr[j] = (int)__popcll(Bmask[myidx[j]] & below);
    *(int4*)&rnk_g[(size_t)bid * 512 + lane * 8]     = make_int4(rr[0], rr[1], rr[2], rr[3]);
    *(int4*)&rnk_g[(size_t)bid * 512 + lane * 8 + 4] = make_int4(rr[4], rr[5], rr[6], rr[7]);
    cbe[bid * 64 + lane] = (int)__popcll(Bmask[lane]);
  }
}

// ---------------------------------------------------------------------------
// Per-expert parallel scan: 64 blocks (block = expert e) x 256 thr.
// Thread tid owns rowwise-block tid: 1 cbe read, shuffle+LDS inclusive scan
// -> pref; tpe[e]; psum column total pst[e]. (R20-proven piece, un-bundled.)
__global__ __launch_bounds__(256) void k_scan(const int* __restrict__ cbe,
                                              const float* __restrict__ psum,
                                              int* __restrict__ pref,
                                              int* __restrict__ tpe_g,
                                              float* __restrict__ pst_g) {
  __shared__ int   wsum[4];
  __shared__ float fsum[4];
  const int e = blockIdx.x;
  const int tid = threadIdx.x;
  const int wv = tid >> 6, lane = tid & 63;

  const int c = cbe[tid * 64 + e];
  int incl = c;
#pragma unroll
  for (int o = 1; o < 64; o <<= 1) {
    int n = __shfl_up(incl, o);
    if (lane >= o) incl += n;
  }
  if (lane == 63) wsum[wv] = incl;
  __syncthreads();
  int add = 0;
#pragma unroll
  for (int i = 0; i < 4; ++i) add += (i < wv) ? wsum[i] : 0;
  incl += add;
  pref[tid * 64 + e] = incl - c;
  if (tid == 255) tpe_g[e] = incl;

  float p = psum[(size_t)tid * 128 + e] + psum[(size_t)tid * 128 + 64 + e];
#pragma unroll
  for (int o = 32; o > 0; o >>= 1) p += __shfl_down(p, o);
  if (lane == 0) fsum[wv] = p;
  __syncthreads();
  if (tid == 0) pst_g[e] = (fsum[0] + fsum[1]) + (fsum[2] + fsum[3]);
}

// ---------------------------------------------------------------------------
// Finalize: z-loss (256 partials), expert cumsum -> group/tpe/ebase, lb-loss.
__global__ __launch_bounds__(256) void k_fin(const int* __restrict__ tpe_g,
                                             const float* __restrict__ pst_g,
                                             const float* __restrict__ lsqp,
                                             int* __restrict__ ebase,
                                             float* __restrict__ out) {
  __shared__ float zbuf[4];
  const int tid = threadIdx.x;
  const int wv = tid >> 6, lane = tid & 63;

  float z = lsqp[tid];
#pragma unroll
  for (int o = 32; o > 0; o >>= 1) z += __shfl_down(z, o);
  if (lane == 0) zbuf[wv] = z;
  __syncthreads();
  if (tid == 0) out[O_ZL] = ((zbuf[0] + zbuf[1]) + (zbuf[2] + zbuf[3])) / 16384.0f;

  if (tid < 64) {
    int incl = 0;
    for (int i = 0; i <= tid; ++i) incl += tpe_g[i];
    const int tpe = tpe_g[tid];
    out[O_TPE + tid]   = (float)tpe;
    out[O_GROUP + tid] = (float)incl;
    ebase[tid] = incl - tpe;
    float term = ((float)tpe / 131072.0f) * (pst_g[tid] / 16384.0f) * 64.0f;
#pragma unroll
    for (int o = 32; o > 0; o >>= 1) term += __shfl_down(term, o);
    if (tid == 0) out[O_LB] = term;
  }
}

// ---------------------------------------------------------------------------
// Elementwise scatter: pos = ebase[e] + pref[block][e] + rank.
__global__ __launch_bounds__(256) void k_scatter(const int* __restrict__ flat,
                                                 const int* __restrict__ rnk,
                                                 const int* __restrict__ pref,
                                                 const int* __restrict__ ebase,
                                                 float* __restrict__ out) {
  const int j = blockIdx.x * 256 + threadIdx.x;
  const int e = flat[j];
  const int pos = ebase[e] + pref[(j >> 9) * 64 + e] + rnk[j];
  out[O_IDX + pos] = (float)j;
}

// ---------------------------------------------------------------------------
extern "C" void kernel_launch(void* const* d_in, const int* in_sizes, int n_in,
                              void* d_out, int out_size, void* d_ws, size_t ws_size,
                              hipStream_t stream) {
  (void)in_sizes; (void)n_in; (void)out_size; (void)ws_size;
  const float* x  = (const float*)d_in[0];
  const float* Wm = (const float*)d_in[1];
  float* out = (float*)d_out;
  char*  ws  = (char*)d_ws;

  float*  lsqp   = (float*)(ws + W_LSQP);
  int*    cbe    = (int*)(ws + W_CBE);
  int*    pref   = (int*)(ws + W_PREF);
  int*    tpe_g  = (int*)(ws + W_TPE);
  float*  pst_g  = (float*)(ws + W_PST);
  int*    ebase  = (int*)(ws + W_EBASE);
  float*  psum   = (float*)(ws + W_PSUM);
  int*    flat   = (int*)(ws + W_FLAT);
  int*    rnk    = (int*)(ws + W_RNK);
  short8* wf     = (short8*)(ws + W_WF);
  float*  part   = (float*)(ws + W_PART);

  k_prep   <<<dim3(128),  dim3(256), 0, stream>>>(Wm, wf);
  k_gemm   <<<dim3(NTOK / 64, NSPLIT), dim3(256), 0, stream>>>(x, wf, part);
  k_reduce <<<dim3(1024), dim3(256), 0, stream>>>(part, out + O_LOGITS);
  k_rowwise<<<dim3(256),  dim3(256), 0, stream>>>(out + O_LOGITS, x, Wm, out, psum, lsqp, flat, rnk, cbe);
  k_scan   <<<dim3(64),   dim3(256), 0, stream>>>(cbe, psum, pref, tpe_g, pst_g);
  k_fin    <<<dim3(1),    dim3(256), 0, stream>>>(tpe_g, pst_g, lsqp, ebase, out);
  k_scatter<<<dim3(512),  dim3(256), 0, stream>>>(flat, rnk, pref, ebase, out);
}